// Round 1
// baseline (604.463 us; speedup 1.0000x reference)
//
#include <hip/hip_runtime.h>
#include <cmath>

#define H_ 128
#define W_ 128
#define HW_ 16384
#define C_ 64
#define N_ 8
#define BN_EPS 1e-5f

// ---- workspace layout (float offsets) ----
#define OFF_BUF_OFS   0
#define OFF_BUF_SZ    (N_*18*HW_)          /* 2359296 */
#define XR_BUF_OFS    (OFF_BUF_OFS + OFF_BUF_SZ)
#define XR_BUF_SZ     (N_*C_*HW_)          /* 8388608 */
#define WDEFT_OFS     (XR_BUF_OFS + XR_BUF_SZ)
#define WDEFT_SZ      (C_*C_*9)            /* 36864 */
#define WOFFT_OFS     (WDEFT_OFS + WDEFT_SZ)
#define WOFFT_SZ      (27*C_*9)            /* 15552 */
#define W1T_OFS       (WOFFT_OFS + WOFFT_SZ)
#define W1T_SZ        (9*C_*9)             /* 5184 */

// Transpose weights so the innermost (uniform) reads are contiguous -> s_load chunks.
// wdefT[k][c][o] = w_def[o][c][k];  woffT[c][t][oc] = w_off[oc][c][t];  w1T[c][t][oc] = w1[oc][c][t]
__global__ __launch_bounds__(256) void transpose_w(
    const float* __restrict__ w_off, const float* __restrict__ w_def,
    const float* __restrict__ w1, float* __restrict__ wdefT,
    float* __restrict__ woffT, float* __restrict__ w1T)
{
    int i = blockIdx.x * 256 + threadIdx.x;
    if (i < 36864) {
        int k = i >> 12;          // /4096
        int r = i & 4095;
        int c = r >> 6;
        int o = r & 63;
        wdefT[i] = w_def[o*576 + c*9 + k];
    } else if (i < 36864 + 15552) {
        int j = i - 36864;
        int c = j / 243;
        int r = j % 243;
        int t = r / 27;
        int oc = r % 27;
        woffT[j] = w_off[oc*576 + c*9 + t];
    } else if (i < 57600) {
        int j = i - 52416;
        int c = j / 81;
        int r = j % 81;
        int t = r / 9;
        int oc = r % 9;
        w1T[j] = w1[oc*576 + c*9 + t];
    }
}

// conv3x3 producing 27 channels; ch 0..17 -> off_buf, ch 18..26 -> filt output (raw)
__global__ __launch_bounds__(256) void conv27_kernel(
    const float* __restrict__ x, const float* __restrict__ wT,
    float* __restrict__ off_buf, float* __restrict__ filt_out)
{
    const int tx = threadIdx.x, ty = threadIdx.y;
    const int hh = blockIdx.y * 16 + ty;
    const int ww = blockIdx.x * 16 + tx;
    const int n  = blockIdx.z;

    int  tofs[9];
    bool tok[9];
    #pragma unroll
    for (int t = 0; t < 9; t++) {
        int yy = hh + t/3 - 1, xx = ww + t%3 - 1;
        tok[t] = ((unsigned)yy < (unsigned)H_) && ((unsigned)xx < (unsigned)W_);
        int cy = min(max(yy, 0), H_-1), cx = min(max(xx, 0), W_-1);
        tofs[t] = cy * W_ + cx;
    }

    float acc[27];
    #pragma unroll
    for (int i = 0; i < 27; i++) acc[i] = 0.f;

    const float* xb = x + (size_t)n * C_ * HW_;
    #pragma unroll 1
    for (int c = 0; c < C_; c++) {
        const float* xp = xb + c * HW_;
        float xv[9];
        #pragma unroll
        for (int t = 0; t < 9; t++) xv[t] = tok[t] ? xp[tofs[t]] : 0.f;
        const float* wp = wT + c * 243;   // uniform address -> scalar loads
        #pragma unroll
        for (int t = 0; t < 9; t++) {
            #pragma unroll
            for (int oc = 0; oc < 27; oc++)
                acc[oc] = fmaf(xv[t], wp[t*27 + oc], acc[oc]);
        }
    }
    const int pix = hh * W_ + ww;
    float* ob = off_buf + (size_t)n * 18 * HW_ + pix;
    #pragma unroll
    for (int oc = 0; oc < 18; oc++) ob[oc * HW_] = acc[oc];
    float* fb = filt_out + (size_t)n * 9 * HW_ + pix;
    #pragma unroll
    for (int oc = 0; oc < 9; oc++) fb[oc * HW_] = acc[18 + oc];
}

// deformable conv (bilinear gather) + residual add: xr = x + deform(x, offset, w_def)
__global__ __launch_bounds__(256) void deform_kernel(
    const float* __restrict__ x, const float* __restrict__ off_buf,
    const float* __restrict__ wT, float* __restrict__ xr)
{
    const int tx = threadIdx.x, ty = threadIdx.y;
    const int hh = blockIdx.y * 16 + ty;
    const int ww = blockIdx.x * 16 + tx;
    const int n  = blockIdx.z;
    const int pix = hh * W_ + ww;
    const float* xb = x + (size_t)n * C_ * HW_;
    const float* ob = off_buf + (size_t)n * 18 * HW_ + pix;

    float acc[64];
    #pragma unroll
    for (int i = 0; i < 64; i++) acc[i] = 0.f;

    #pragma unroll 1
    for (int k = 0; k < 9; k++) {
        float offy = ob[(2*k) * HW_];
        float offx = ob[(2*k+1) * HW_];
        float py = (float)(hh + k/3 - 1) + offy;
        float px = (float)(ww + k%3 - 1) + offx;
        float y0f = floorf(py), x0f = floorf(px);
        float wy1 = py - y0f, wx1 = px - x0f;
        float wy0 = 1.f - wy1, wx0 = 1.f - wx1;
        int y0 = (int)y0f, x0 = (int)x0f;
        int y1 = y0 + 1,   x1 = x0 + 1;
        float vy0 = ((unsigned)y0 < (unsigned)H_) ? 1.f : 0.f;
        float vy1 = ((unsigned)y1 < (unsigned)H_) ? 1.f : 0.f;
        float vx0 = ((unsigned)x0 < (unsigned)W_) ? 1.f : 0.f;
        float vx1 = ((unsigned)x1 < (unsigned)W_) ? 1.f : 0.f;
        float w00 = wy0*wx0*vy0*vx0;
        float w01 = wy0*wx1*vy0*vx1;
        float w10 = wy1*wx0*vy1*vx0;
        float w11 = wy1*wx1*vy1*vx1;
        int cy0 = min(max(y0, 0), H_-1), cy1 = min(max(y1, 0), H_-1);
        int cx0 = min(max(x0, 0), W_-1), cx1 = min(max(x1, 0), W_-1);
        int i00 = cy0*W_ + cx0, i01 = cy0*W_ + cx1;
        int i10 = cy1*W_ + cx0, i11 = cy1*W_ + cx1;

        float p00 = xb[i00], p01 = xb[i01], p10 = xb[i10], p11 = xb[i11];
        #pragma unroll 2
        for (int c = 0; c < C_; c++) {
            float s = p00*w00 + p01*w01 + p10*w10 + p11*w11;
            if (c + 1 < C_) {           // prefetch next channel's corners
                const float* xq = xb + (c+1) * HW_;
                p00 = xq[i00]; p01 = xq[i01]; p10 = xq[i10]; p11 = xq[i11];
            }
            const float* wp = wT + (k*64 + c) * 64;  // uniform -> scalar loads
            #pragma unroll
            for (int o = 0; o < 64; o++)
                acc[o] = fmaf(s, wp[o], acc[o]);
        }
    }
    const float* xq = xb + pix;
    float* xo = xr + (size_t)n * C_ * HW_ + pix;
    #pragma unroll
    for (int o = 0; o < 64; o++) xo[o * HW_] = acc[o] + xq[o * HW_];
}

// conv3x3 (9 out ch) + BN (inference) + ReLU
__global__ __launch_bounds__(256) void conv9_bn_kernel(
    const float* __restrict__ xr, const float* __restrict__ wT,
    const float* __restrict__ gamma, const float* __restrict__ beta,
    const float* __restrict__ mean, const float* __restrict__ var,
    float* __restrict__ out)
{
    const int tx = threadIdx.x, ty = threadIdx.y;
    const int hh = blockIdx.y * 16 + ty;
    const int ww = blockIdx.x * 16 + tx;
    const int n  = blockIdx.z;

    int  tofs[9];
    bool tok[9];
    #pragma unroll
    for (int t = 0; t < 9; t++) {
        int yy = hh + t/3 - 1, xx = ww + t%3 - 1;
        tok[t] = ((unsigned)yy < (unsigned)H_) && ((unsigned)xx < (unsigned)W_);
        int cy = min(max(yy, 0), H_-1), cx = min(max(xx, 0), W_-1);
        tofs[t] = cy * W_ + cx;
    }

    float acc[9];
    #pragma unroll
    for (int i = 0; i < 9; i++) acc[i] = 0.f;

    const float* xb = xr + (size_t)n * C_ * HW_;
    #pragma unroll 1
    for (int c = 0; c < C_; c++) {
        const float* xp = xb + c * HW_;
        float xv[9];
        #pragma unroll
        for (int t = 0; t < 9; t++) xv[t] = tok[t] ? xp[tofs[t]] : 0.f;
        const float* wp = wT + c * 81;    // uniform -> scalar loads
        #pragma unroll
        for (int t = 0; t < 9; t++) {
            #pragma unroll
            for (int oc = 0; oc < 9; oc++)
                acc[oc] = fmaf(xv[t], wp[t*9 + oc], acc[oc]);
        }
    }
    const int pix = hh * W_ + ww;
    float* po = out + (size_t)n * 9 * HW_ + pix;
    #pragma unroll
    for (int oc = 0; oc < 9; oc++) {
        float sc = gamma[oc] * rsqrtf(var[oc] + BN_EPS);
        float sh = beta[oc] - mean[oc] * sc;
        float h  = fmaxf(fmaf(acc[oc], sc, sh), 0.f);
        po[oc * HW_] = h;
    }
}

extern "C" void kernel_launch(void* const* d_in, const int* in_sizes, int n_in,
                              void* d_out, int out_size, void* d_ws, size_t ws_size,
                              hipStream_t stream)
{
    const float* x     = (const float*)d_in[0];
    const float* w_off = (const float*)d_in[1];
    const float* w_def = (const float*)d_in[2];
    const float* w1    = (const float*)d_in[3];
    const float* gamma = (const float*)d_in[4];
    const float* beta  = (const float*)d_in[5];
    const float* mean  = (const float*)d_in[6];
    const float* var   = (const float*)d_in[7];
    float* out = (float*)d_out;

    float* ws      = (float*)d_ws;
    float* off_buf = ws + OFF_BUF_OFS;
    float* xr_buf  = ws + XR_BUF_OFS;
    float* wdefT   = ws + WDEFT_OFS;
    float* woffT   = ws + WOFFT_OFS;
    float* w1T     = ws + W1T_OFS;

    float* h_out    = out;
    float* filt_out = out + (size_t)N_ * 9 * HW_;

    transpose_w<<<dim3(225), dim3(256), 0, stream>>>(w_off, w_def, w1, wdefT, woffT, w1T);

    dim3 grid(W_/16, H_/16, N_);   // 8,8,8
    dim3 blk(16, 16);
    conv27_kernel<<<grid, blk, 0, stream>>>(x, woffT, off_buf, filt_out);
    deform_kernel<<<grid, blk, 0, stream>>>(x, off_buf, wdefT, xr_buf);
    conv9_bn_kernel<<<grid, blk, 0, stream>>>(xr_buf, w1T, gamma, beta, mean, var, h_out);
}